// Round 16
// baseline (274.166 us; speedup 1.0000x reference)
//
#include <hip/hip_runtime.h>
#include <math.h>

// ---------------------------------------------------------------------------
// RoadNetworkEncoder: 2x GATv2 (road) + 2x GCN (zone), f32 in/out, H=128.
// Round 16: 32-row MT=2 dual GEMMs (feat_gemm1, road layer-2). Round-15's
// 64-row MT=4 duals ran at 24% occupancy (64 acc regs -> 3 waves/SIMD) and
// were pure exposed-latency (VALU 9%, MFMA 3%). 32-row: acc 32 regs, LDS
// 8.7KB, 2x grid -> ~2.5x resident waves. Zone GEMMs keep 64-row path.
// ---------------------------------------------------------------------------

typedef __attribute__((ext_vector_type(8))) short bf16x8;
typedef __attribute__((ext_vector_type(4))) float f32x4;

static __device__ __forceinline__ unsigned short f2b(float f) {
  unsigned u = __float_as_uint(f);
  u = (u + 0x7FFFu + ((u >> 16) & 1u)) >> 16;  // RNE
  return (unsigned short)u;
}
static __device__ __forceinline__ float b2f(unsigned short u) {
  return __uint_as_float(((unsigned)u) << 16);
}

// ---- 6x W[128][128] f32 -> WT[n][k] bf16 (transpose + cast) ----
__global__ __launch_bounds__(256) void wcast6(
    const float* __restrict__ W0, const float* __restrict__ W1, const float* __restrict__ W2,
    const float* __restrict__ W3, const float* __restrict__ W4, const float* __restrict__ W5,
    unsigned short* __restrict__ WT) {
  int b = blockIdx.x >> 6;
  int idx = (blockIdx.x & 63) * 256 + threadIdx.x;
  const float* W = (b == 0) ? W0 : (b == 1) ? W1 : (b == 2) ? W2 : (b == 3) ? W3 : (b == 4) ? W4 : W5;
  int n = idx >> 7, k = idx & 127;
  WT[b * 16384 + idx] = f2b(W[k * 128 + n]);
}

// ---- fold the non-id feature segments: FL[mat][36][128] f32 --------------
__global__ __launch_bounds__(128) void feat_fold(
    const float* __restrict__ Wl, const float* __restrict__ blv,
    const float* __restrict__ Wr, const float* __restrict__ brv,
    const float* __restrict__ lenW, const float* __restrict__ lenb,
    const float* __restrict__ type_emb,
    const float* __restrict__ lonW, const float* __restrict__ lonb,
    const float* __restrict__ latW, const float* __restrict__ latb,
    float* __restrict__ FL) {
  int b = blockIdx.x;           // 0..71
  int mat = b / 36, r = b % 36;
  int n = threadIdx.x;          // 0..127
  const float* W = mat ? Wr : Wl;
  const float* bias = mat ? brv : blv;
  float s = 0.f;
  if (r < 32) {
#pragma unroll
    for (int j = 0; j < 16; ++j) s += type_emb[r * 16 + j] * W[(80 + j) * 128 + n];
  } else if (r == 32) {
#pragma unroll
    for (int j = 0; j < 16; ++j) s += lenW[j] * W[(64 + j) * 128 + n];
  } else if (r == 33) {
#pragma unroll
    for (int j = 0; j < 16; ++j) s += lonW[j] * W[(96 + j) * 128 + n];
  } else if (r == 34) {
#pragma unroll
    for (int j = 0; j < 16; ++j) s += latW[j] * W[(112 + j) * 128 + n];
  } else {
    s = bias[n];
#pragma unroll
    for (int j = 0; j < 16; ++j)
      s += lenb[j] * W[(64 + j) * 128 + n] + lonb[j] * W[(96 + j) * 128 + n] +
           latb[j] * W[(112 + j) * 128 + n];
  }
  FL[(mat * 36 + r) * 128 + n] = s;
}

// ------------------------- CSR build (road + zone combined) ---------------

__global__ __launch_bounds__(256) void hist2(const int* __restrict__ dstR, int E,
                                             const int* __restrict__ dstZ, int EZ,
                                             int* __restrict__ histR, int* __restrict__ histZ) {
  int e = blockIdx.x * 256 + threadIdx.x;
  if (e < E) atomicAdd(histR + dstR[e], 1);
  else if (e - E < EZ) atomicAdd(histZ + dstZ[e - E], 1);
}

__global__ __launch_bounds__(256) void scan_local2(
    const int* __restrict__ inR, int* __restrict__ outR, int* __restrict__ bsumR, int nR, int nbR,
    const int* __restrict__ inZ, int* __restrict__ outZ, int* __restrict__ bsumZ, int nZ) {
  __shared__ int lds[256];
  const int* in; int* out; int* bsum; int n; int bid;
  if ((int)blockIdx.x < nbR) { in = inR; out = outR; bsum = bsumR; n = nR; bid = blockIdx.x; }
  else { in = inZ; out = outZ; bsum = bsumZ; n = nZ; bid = blockIdx.x - nbR; }
  int t = threadIdx.x;
  int base = bid * 1024 + t * 4;
  int v0 = base + 0 < n ? in[base + 0] : 0;
  int v1 = base + 1 < n ? in[base + 1] : 0;
  int v2 = base + 2 < n ? in[base + 2] : 0;
  int v3 = base + 3 < n ? in[base + 3] : 0;
  int s = v0 + v1 + v2 + v3;
  lds[t] = s;
  __syncthreads();
  for (int off = 1; off < 256; off <<= 1) {
    int x = (t >= off) ? lds[t - off] : 0;
    __syncthreads();
    if (t >= off) lds[t] += x;
    __syncthreads();
  }
  int excl = lds[t] - s;
  if (t == 255) bsum[bid] = lds[255];
  if (base + 0 < n) out[base + 0] = excl;
  if (base + 1 < n) out[base + 1] = excl + v0;
  if (base + 2 < n) out[base + 2] = excl + v0 + v1;
  if (base + 3 < n) out[base + 3] = excl + v0 + v1 + v2;
}

__global__ __launch_bounds__(256) void scan_bsum2(int* __restrict__ bsumR, int nbR,
                                                  int* __restrict__ bsumZ, int nbZ) {
  __shared__ int lds[256];
  int* bsum = blockIdx.x ? bsumZ : bsumR;
  int nb = blockIdx.x ? nbZ : nbR;
  int t = threadIdx.x;
  int v = (t < nb) ? bsum[t] : 0;
  lds[t] = v;
  __syncthreads();
  for (int off = 1; off < 256; off <<= 1) {
    int x = (t >= off) ? lds[t - off] : 0;
    __syncthreads();
    if (t >= off) lds[t] += x;
    __syncthreads();
  }
  if (t < nb) bsum[t] = lds[t] - v;
}

// adds block offsets AND seeds cursor = rowstart
__global__ __launch_bounds__(256) void scan_add2(
    int* __restrict__ outR, int* __restrict__ curR, const int* __restrict__ bsumR, int nR,
    int* __restrict__ outZ, int* __restrict__ curZ, const int* __restrict__ bsumZ, int nZ) {
  int i = blockIdx.x * 256 + threadIdx.x;
  if (i < nR) {
    int v = outR[i] + bsumR[i >> 10];
    outR[i] = v;
    curR[i] = v;
  } else if (i - nR < nZ) {
    int j = i - nR;
    int v = outZ[j] + bsumZ[j >> 10];
    outZ[j] = v;
    curZ[j] = v;
  }
}

__global__ __launch_bounds__(256) void scatter2(
    const int* __restrict__ srcR, const int* __restrict__ dstR, const float* __restrict__ ia,
    int* __restrict__ cursor, int4* __restrict__ csr_pack, int E,
    const int* __restrict__ srcZ, const int* __restrict__ dstZ, const float* __restrict__ zw,
    int* __restrict__ zcursor, int2* __restrict__ zcsr_pack, int EZ) {
  int e = blockIdx.x * 256 + threadIdx.x;
  if (e < E) {
    int d = dstR[e];
    int idx = atomicAdd(cursor + d, 1);
    int4 pk;
    pk.x = srcR[e];
    pk.y = __float_as_int(ia[2 * e]);
    pk.z = __float_as_int(ia[2 * e + 1]);
    pk.w = 0;
    csr_pack[idx] = pk;
  } else if (e - E < EZ) {
    int ez = e - E;
    int d = dstZ[ez];
    int idx = atomicAdd(zcursor + d, 1);
    int2 pk;
    pk.x = srcZ[ez];
    pk.y = __float_as_int(zw[ez]);
    zcsr_pack[idx] = pk;
  }
}

__global__ __launch_bounds__(256) void meanea_dinv_k(
    const int* __restrict__ rowstart, const int* __restrict__ hist,
    const int4* __restrict__ csr_pack, float2* __restrict__ mea, int N,
    const int* __restrict__ zrowstart, const int* __restrict__ zhist,
    const int2* __restrict__ zcsr_pack, float* __restrict__ dinv, int NZ) {
  int i = blockIdx.x * 256 + threadIdx.x;
  if (i < N) {
    int st = rowstart[i], deg = hist[i];
    float a = 0.f, b = 0.f;
    for (int k = 0; k < deg; ++k) {
      int4 pk = csr_pack[st + k];
      a += __int_as_float(pk.y);
      b += __int_as_float(pk.z);
    }
    float c = deg > 0 ? 1.f / (float)deg : 0.f;
    mea[i] = make_float2(a * c, b * c);
  } else if (i - N < NZ) {
    int d = i - N;
    int st = zrowstart[d], deg = zhist[d];
    float s = 1.f;
    for (int k = 0; k < deg; ++k) s += __int_as_float(zcsr_pack[st + k].y);
    dinv[d] = rsqrtf(s);
  }
}

// ------------------------- shared 64-row GEMM core (zone) -----------------
template <int DUAL>
__device__ __forceinline__ void gemm_core(
    unsigned short (*Xs)[136],
    const unsigned short* __restrict__ WlT, const unsigned short* __restrict__ WrT,
    const float* __restrict__ bl, const float* __restrict__ br,
    unsigned short* __restrict__ Yl, unsigned short* __restrict__ Yr,
    int row0, int N) {
  constexpr int MT = DUAL ? 4 : 2;
  int t = threadIdx.x;
  int w = t >> 6, lane = t & 63;
  int mb = DUAL ? 0 : (w >> 1) * 2;
  int ncol0 = (w & 1) * 64;
  const bool isR = DUAL && (w >> 1);
  const unsigned short* WTw = isR ? WrT : WlT;
  const float* bias = isR ? br : bl;
  int l15 = lane & 15, l4 = lane >> 4;

  bf16x8 b0[4], b1[4];
#pragma unroll
  for (int nt = 0; nt < 4; ++nt) {
    const unsigned short* p = WTw + (size_t)(ncol0 + nt * 16 + l15) * 128 + l4 * 8;
    b0[nt] = *reinterpret_cast<const bf16x8*>(p);
  }
  f32x4 acc[MT][4];
#pragma unroll
  for (int mt = 0; mt < MT; ++mt)
#pragma unroll
    for (int nt = 0; nt < 4; ++nt)
      acc[mt][nt] = (f32x4){0.f, 0.f, 0.f, 0.f};

#pragma unroll
  for (int ks = 0; ks < 4; ++ks) {
    bf16x8* bc = (ks & 1) ? b1 : b0;
    bf16x8* bn = (ks & 1) ? b0 : b1;
    if (ks < 3) {
#pragma unroll
      for (int nt = 0; nt < 4; ++nt) {
        const unsigned short* p = WTw + (size_t)(ncol0 + nt * 16 + l15) * 128 + (ks + 1) * 32 + l4 * 8;
        bn[nt] = *reinterpret_cast<const bf16x8*>(p);
      }
    }
    bf16x8 a[MT];
#pragma unroll
    for (int mt = 0; mt < MT; ++mt)
      a[mt] = *reinterpret_cast<const bf16x8*>(&Xs[(mb + mt) * 16 + l15][ks * 32 + l4 * 8]);
#pragma unroll
    for (int mt = 0; mt < MT; ++mt)
#pragma unroll
      for (int nt = 0; nt < 4; ++nt)
        acc[mt][nt] = __builtin_amdgcn_mfma_f32_16x16x32_bf16(bc[nt], a[mt], acc[mt][nt], 0, 0, 0);
  }

  const int passes = DUAL ? 2 : 1;
#pragma unroll
  for (int pass = 0; pass < passes; ++pass) {
    __syncthreads();
    if (!DUAL || (w >> 1) == pass) {
#pragma unroll
      for (int nt = 0; nt < 4; ++nt) {
        int c0 = ncol0 + nt * 16 + l4 * 4;
        float4 bv = make_float4(0.f, 0.f, 0.f, 0.f);
        if (bias) bv = *reinterpret_cast<const float4*>(bias + c0);
#pragma unroll
        for (int mt = 0; mt < MT; ++mt) {
          int rl = (mb + mt) * 16 + l15;
          ushort4 pk;
          pk.x = f2b(acc[mt][nt][0] + bv.x);
          pk.y = f2b(acc[mt][nt][1] + bv.y);
          pk.z = f2b(acc[mt][nt][2] + bv.z);
          pk.w = f2b(acc[mt][nt][3] + bv.w);
          *reinterpret_cast<ushort4*>(&Xs[rl][c0]) = pk;
        }
      }
    }
    __syncthreads();
    unsigned short* Yt = DUAL ? (pass ? Yr : Yl) : Yl;
#pragma unroll
    for (int q = 0; q < 4; ++q) {
      int lin = q * 256 + t;
      int r = lin >> 4, cc = (lin & 15) * 8;
      int row = row0 + r;
      if (row < N)
        *reinterpret_cast<bf16x8*>(Yt + (size_t)row * 128 + cc) =
            *reinterpret_cast<const bf16x8*>(&Xs[r][cc]);
    }
  }
}

// ------------------------- zone GEMM (64-row, XBF input select) -----------
template <int DUAL, int XBF>
__global__ __launch_bounds__(256) void gemm_mfma(
    const void* __restrict__ Xv,
    const unsigned short* __restrict__ WlT, const unsigned short* __restrict__ WrT,
    const float* __restrict__ bl, const float* __restrict__ br,
    unsigned short* __restrict__ Yl, unsigned short* __restrict__ Yr, int N) {
  __shared__ __align__(16) unsigned short Xs[64][136];
  int t = threadIdx.x;
  int row0 = blockIdx.x * 64;
  if (XBF) {
    const unsigned short* Xb = (const unsigned short*)Xv;
#pragma unroll
    for (int q = 0; q < 8; ++q) {
      int lin = q * 256 + t;
      int r = lin >> 5, kf = (lin & 31) * 4;
      int row = min(row0 + r, N - 1);
      *reinterpret_cast<ushort4*>(&Xs[r][kf]) =
          *reinterpret_cast<const ushort4*>(Xb + (size_t)row * 128 + kf);
    }
  } else {
    const float* Xf = (const float*)Xv;
#pragma unroll
    for (int q = 0; q < 8; ++q) {
      int lin = q * 256 + t;
      int r = lin >> 5, kf = (lin & 31) * 4;
      int row = min(row0 + r, N - 1);
      float4 xv = *reinterpret_cast<const float4*>(Xf + (size_t)row * 128 + kf);
      ushort4 pk;
      pk.x = f2b(xv.x); pk.y = f2b(xv.y); pk.z = f2b(xv.z); pk.w = f2b(xv.w);
      *reinterpret_cast<ushort4*>(&Xs[r][kf]) = pk;
    }
  }
  __syncthreads();
  gemm_core<DUAL>(Xs, WlT, WrT, bl, br, Yl, Yr, row0, N);
}

// ------------------------- 32-row dual GEMM (road layer-2) ----------------
__global__ __launch_bounds__(256) void gemm_dual32(
    const unsigned short* __restrict__ Xb,
    const unsigned short* __restrict__ WlT, const unsigned short* __restrict__ WrT,
    const float* __restrict__ bl, const float* __restrict__ br,
    unsigned short* __restrict__ Yl, unsigned short* __restrict__ Yr, int N) {
  __shared__ __align__(16) unsigned short Xs[32][136];
  int t = threadIdx.x;
  int row0 = blockIdx.x * 32;
  int w = t >> 6, lane = t & 63;
  int ncol0 = (w & 1) * 64;
  const bool isR = (w >> 1);
  const unsigned short* WTw = isR ? WrT : WlT;
  const float* bias = isR ? br : bl;
  int l15 = lane & 15, l4 = lane >> 4;

#pragma unroll
  for (int q = 0; q < 4; ++q) {
    int lin = q * 256 + t;          // 0..1023
    int r = lin >> 5, kf = (lin & 31) * 4;
    int row = min(row0 + r, N - 1);
    *reinterpret_cast<ushort4*>(&Xs[r][kf]) =
        *reinterpret_cast<const ushort4*>(Xb + (size_t)row * 128 + kf);
  }

  bf16x8 b0[4], b1[4];
#pragma unroll
  for (int nt = 0; nt < 4; ++nt) {
    const unsigned short* p = WTw + (size_t)(ncol0 + nt * 16 + l15) * 128 + l4 * 8;
    b0[nt] = *reinterpret_cast<const bf16x8*>(p);
  }
  __syncthreads();

  f32x4 acc[2][4];
#pragma unroll
  for (int mt = 0; mt < 2; ++mt)
#pragma unroll
    for (int nt = 0; nt < 4; ++nt)
      acc[mt][nt] = (f32x4){0.f, 0.f, 0.f, 0.f};

#pragma unroll
  for (int ks = 0; ks < 4; ++ks) {
    bf16x8* bc = (ks & 1) ? b1 : b0;
    bf16x8* bn = (ks & 1) ? b0 : b1;
    if (ks < 3) {
#pragma unroll
      for (int nt = 0; nt < 4; ++nt) {
        const unsigned short* p = WTw + (size_t)(ncol0 + nt * 16 + l15) * 128 + (ks + 1) * 32 + l4 * 8;
        bn[nt] = *reinterpret_cast<const bf16x8*>(p);
      }
    }
    bf16x8 a[2];
#pragma unroll
    for (int mt = 0; mt < 2; ++mt)
      a[mt] = *reinterpret_cast<const bf16x8*>(&Xs[mt * 16 + l15][ks * 32 + l4 * 8]);
#pragma unroll
    for (int mt = 0; mt < 2; ++mt)
#pragma unroll
      for (int nt = 0; nt < 4; ++nt)
        acc[mt][nt] = __builtin_amdgcn_mfma_f32_16x16x32_bf16(bc[nt], a[mt], acc[mt][nt], 0, 0, 0);
  }

#pragma unroll
  for (int pass = 0; pass < 2; ++pass) {
    __syncthreads();
    if ((int)isR == pass) {
#pragma unroll
      for (int nt = 0; nt < 4; ++nt) {
        int c0 = ncol0 + nt * 16 + l4 * 4;
        float4 bv = *reinterpret_cast<const float4*>(bias + c0);
#pragma unroll
        for (int mt = 0; mt < 2; ++mt) {
          int rl = mt * 16 + l15;
          ushort4 pk;
          pk.x = f2b(acc[mt][nt][0] + bv.x);
          pk.y = f2b(acc[mt][nt][1] + bv.y);
          pk.z = f2b(acc[mt][nt][2] + bv.z);
          pk.w = f2b(acc[mt][nt][3] + bv.w);
          *reinterpret_cast<ushort4*>(&Xs[rl][c0]) = pk;
        }
      }
    }
    __syncthreads();
    unsigned short* Yt = pass ? Yr : Yl;
#pragma unroll
    for (int q = 0; q < 2; ++q) {
      int lin = q * 256 + t;          // 0..511
      int r = lin >> 4, cc = (lin & 15) * 8;
      int row = row0 + r;
      if (row < N)
        *reinterpret_cast<bf16x8*>(Yt + (size_t)row * 128 + cc) =
            *reinterpret_cast<const bf16x8*>(&Xs[r][cc]);
    }
  }
}

// ------------------------- 32-row fused: id_emb K=64 + fold epilogue ------
__global__ __launch_bounds__(256) void feat_gemm1(
    const float* __restrict__ id_emb,
    const float* __restrict__ alen, const int* __restrict__ atype,
    const float* __restrict__ alon, const float* __restrict__ alat,
    const unsigned short* __restrict__ WlT, const unsigned short* __restrict__ WrT,
    const float* __restrict__ FLl, const float* __restrict__ FLr,
    unsigned short* __restrict__ Yl, unsigned short* __restrict__ Yr, int N) {
  __shared__ __align__(16) unsigned short Xs[32][136];
  int t = threadIdx.x;
  int row0 = blockIdx.x * 32;
  int w = t >> 6, lane = t & 63;
  int ncol0 = (w & 1) * 64;
  const bool isR = (w >> 1);
  const unsigned short* WTw = isR ? WrT : WlT;
  const float* FL = isR ? FLr : FLl;
  int l15 = lane & 15, l4 = lane >> 4;

  bf16x8 b0[4], b1[4];
#pragma unroll
  for (int nt = 0; nt < 4; ++nt) {
    const unsigned short* p = WTw + (size_t)(ncol0 + nt * 16 + l15) * 128 + l4 * 8;
    b0[nt] = *reinterpret_cast<const bf16x8*>(p);
    b1[nt] = *reinterpret_cast<const bf16x8*>(p + 32);
  }

  // stage id_emb (32 rows x 64 k) as bf16
#pragma unroll
  for (int q = 0; q < 2; ++q) {
    int lin = q * 256 + t;          // 0..511
    int r = lin >> 4, kf = (lin & 15) * 4;
    int row = min(row0 + r, N - 1);
    float4 xv = *reinterpret_cast<const float4*>(id_emb + (size_t)row * 64 + kf);
    ushort4 pk;
    pk.x = f2b(xv.x); pk.y = f2b(xv.y); pk.z = f2b(xv.z); pk.w = f2b(xv.w);
    *reinterpret_cast<ushort4*>(&Xs[r][kf]) = pk;
  }
  __syncthreads();

  f32x4 acc[2][4];
#pragma unroll
  for (int mt = 0; mt < 2; ++mt)
#pragma unroll
    for (int nt = 0; nt < 4; ++nt)
      acc[mt][nt] = (f32x4){0.f, 0.f, 0.f, 0.f};

#pragma unroll
  for (int ks = 0; ks < 2; ++ks) {
    bf16x8* bc = ks ? b1 : b0;
    bf16x8 a[2];
#pragma unroll
    for (int mt = 0; mt < 2; ++mt)
      a[mt] = *reinterpret_cast<const bf16x8*>(&Xs[mt * 16 + l15][ks * 32 + l4 * 8]);
#pragma unroll
    for (int mt = 0; mt < 2; ++mt)
#pragma unroll
      for (int nt = 0; nt < 4; ++nt)
        acc[mt][nt] = __builtin_amdgcn_mfma_f32_16x16x32_bf16(bc[nt], a[mt], acc[mt][nt], 0, 0, 0);
  }

  float lenv[2], lonv[2], latv[2];
  int tyv[2];
#pragma unroll
  for (int mt = 0; mt < 2; ++mt) {
    int row = min(row0 + mt * 16 + l15, N - 1);
    lenv[mt] = alen[row]; lonv[mt] = alon[row]; latv[mt] = alat[row];
    tyv[mt] = atype[row];
  }

#pragma unroll
  for (int pass = 0; pass < 2; ++pass) {
    __syncthreads();
    if ((int)isR == pass) {
#pragma unroll
      for (int nt = 0; nt < 4; ++nt) {
        int c0 = ncol0 + nt * 16 + l4 * 4;
        float4 vl = *reinterpret_cast<const float4*>(FL + 32 * 128 + c0);
        float4 vo = *reinterpret_cast<const float4*>(FL + 33 * 128 + c0);
        float4 va = *reinterpret_cast<const float4*>(FL + 34 * 128 + c0);
        float4 vc = *reinterpret_cast<const float4*>(FL + 35 * 128 + c0);
#pragma unroll
        for (int mt = 0; mt < 2; ++mt) {
          float4 tv = *reinterpret_cast<const float4*>(FL + tyv[mt] * 128 + c0);
          ushort4 pk;
          pk.x = f2b(acc[mt][nt][0] + lenv[mt] * vl.x + lonv[mt] * vo.x + latv[mt] * va.x + tv.x + vc.x);
          pk.y = f2b(acc[mt][nt][1] + lenv[mt] * vl.y + lonv[mt] * vo.y + latv[mt] * va.y + tv.y + vc.y);
          pk.z = f2b(acc[mt][nt][2] + lenv[mt] * vl.z + lonv[mt] * vo.z + latv[mt] * va.z + tv.z + vc.z);
          pk.w = f2b(acc[mt][nt][3] + lenv[mt] * vl.w + lonv[mt] * vo.w + latv[mt] * va.w + tv.w + vc.w);
          *reinterpret_cast<ushort4*>(&Xs[mt * 16 + l15][c0]) = pk;
        }
      }
    }
    __syncthreads();
    unsigned short* Yt = pass ? Yr : Yl;
#pragma unroll
    for (int q = 0; q < 2; ++q) {
      int lin = q * 256 + t;
      int r = lin >> 4, cc = (lin & 15) * 8;
      int row = row0 + r;
      if (row < N)
        *reinterpret_cast<bf16x8*>(Yt + (size_t)row * 128 + cc) =
            *reinterpret_cast<const bf16x8*>(&Xs[r][cc]);
    }
  }
}

// ------------------------- GAT per-node pull (no-max softmax, batch-4) ----
__device__ __forceinline__ float4 gat_one(
    const unsigned short* __restrict__ xl, float4 xr4,
    int d, int st, int deg, float2 me, int lane,
    const int4* __restrict__ csr_pack,
    float4 w0, float4 w1, float4 at) {
  float denom;
  float4 acc;
  {
    ushort4 av = *reinterpret_cast<const ushort4*>(xl + (size_t)d * 128 + lane * 4);
    float4 a;
    a.x = b2f(av.x); a.y = b2f(av.y); a.z = b2f(av.z); a.w = b2f(av.w);
    float4 v;
    v.x = a.x + xr4.x + me.x * w0.x + me.y * w1.x; v.x = v.x > 0.f ? v.x : 0.2f * v.x;
    v.y = a.y + xr4.y + me.x * w0.y + me.y * w1.y; v.y = v.y > 0.f ? v.y : 0.2f * v.y;
    v.z = a.z + xr4.z + me.x * w0.z + me.y * w1.z; v.z = v.z > 0.f ? v.z : 0.2f * v.z;
    v.w = a.w + xr4.w + me.x * w0.w + me.y * w1.w; v.w = v.w > 0.f ? v.w : 0.2f * v.w;
    float p = v.x * at.x + v.y * at.y + v.z * at.z + v.w * at.w;
#pragma unroll
    for (int off = 16; off; off >>= 1) p += __shfl_xor(p, off, 32);
    float wgt = __expf(p);
    denom = wgt;
    acc.x = wgt * a.x; acc.y = wgt * a.y; acc.z = wgt * a.z; acc.w = wgt * a.w;
  }
  for (int base = 0; base < deg; base += 32) {
    int rem = deg - base;
    int chunk = rem < 32 ? rem : 32;
    int k = st + base + lane;
    int sidx = 0;
    float2 eav = make_float2(0.f, 0.f);
    if (lane < chunk) {
      int4 pk = csr_pack[k];
      sidx = pk.x;
      eav = make_float2(__int_as_float(pk.y), __int_as_float(pk.z));
    }
    auto edge = [&](ushort4 avv, int i) {
      float ea0 = __shfl(eav.x, i, 32);
      float ea1 = __shfl(eav.y, i, 32);
      float4 a;
      a.x = b2f(avv.x); a.y = b2f(avv.y); a.z = b2f(avv.z); a.w = b2f(avv.w);
      float4 v;
      v.x = a.x + xr4.x + ea0 * w0.x + ea1 * w1.x; v.x = v.x > 0.f ? v.x : 0.2f * v.x;
      v.y = a.y + xr4.y + ea0 * w0.y + ea1 * w1.y; v.y = v.y > 0.f ? v.y : 0.2f * v.y;
      v.z = a.z + xr4.z + ea0 * w0.z + ea1 * w1.z; v.z = v.z > 0.f ? v.z : 0.2f * v.z;
      v.w = a.w + xr4.w + ea0 * w0.w + ea1 * w1.w; v.w = v.w > 0.f ? v.w : 0.2f * v.w;
      float p = v.x * at.x + v.y * at.y + v.z * at.z + v.w * at.w;
#pragma unroll
      for (int off = 16; off; off >>= 1) p += __shfl_xor(p, off, 32);
      float wgt = __expf(p);
      denom += wgt;
      acc.x += wgt * a.x; acc.y += wgt * a.y; acc.z += wgt * a.z; acc.w += wgt * a.w;
    };
    for (int i0 = 0; i0 < chunk; i0 += 4) {
      int cnt = chunk - i0; if (cnt > 4) cnt = 4;
      int s0 = __shfl(sidx, i0 + 0, 32);
      int s1 = __shfl(sidx, i0 + 1, 32);
      int s2 = __shfl(sidx, i0 + 2, 32);
      int s3 = __shfl(sidx, i0 + 3, 32);
      ushort4 a0, a1, a2, a3;
      a0 = *reinterpret_cast<const ushort4*>(xl + (size_t)s0 * 128 + lane * 4);
      if (cnt > 1) a1 = *reinterpret_cast<const ushort4*>(xl + (size_t)s1 * 128 + lane * 4);
      if (cnt > 2) a2 = *reinterpret_cast<const ushort4*>(xl + (size_t)s2 * 128 + lane * 4);
      if (cnt > 3) a3 = *reinterpret_cast<const ushort4*>(xl + (size_t)s3 * 128 + lane * 4);
      edge(a0, i0 + 0);
      if (cnt > 1) edge(a1, i0 + 1);
      if (cnt > 2) edge(a2, i0 + 2);
      if (cnt > 3) edge(a3, i0 + 3);
    }
  }
  float inv = 1.f / denom;
  float4 o;
  o.x = acc.x * inv; o.y = acc.y * inv; o.z = acc.z * inv; o.w = acc.w * inv;
  return o;
}

template <int OUTBF>
__global__ __launch_bounds__(256) void gat_node(
    const unsigned short* __restrict__ xl, const unsigned short* __restrict__ xr,
    const int* __restrict__ rowstart, const int* __restrict__ hist,
    const int4* __restrict__ csr_pack,
    const float2* __restrict__ mean_ea,
    const float* __restrict__ We, const float* __restrict__ att, const float* __restrict__ bias,
    void* __restrict__ out, int N, int relu) {
  __shared__ float sW0[128], sW1[128], sAtt[128], sBias[128];
  int t = threadIdx.x;
  if (t < 128) { sW0[t] = We[t]; sW1[t] = We[128 + t]; }
  else { int j = t - 128; sAtt[j] = att[j]; sBias[j] = bias[j]; }
  __syncthreads();
  int grp = t >> 5, lane = t & 31;
  int d = blockIdx.x * 8 + grp;
  if (d >= N) return;
  float4 w0 = *reinterpret_cast<const float4*>(sW0 + lane * 4);
  float4 w1 = *reinterpret_cast<const float4*>(sW1 + lane * 4);
  float4 at = *reinterpret_cast<const float4*>(sAtt + lane * 4);
  float4 bv = *reinterpret_cast<const float4*>(sBias + lane * 4);
  ushort4 xrv = *reinterpret_cast<const ushort4*>(xr + (size_t)d * 128 + lane * 4);
  float4 xr4;
  xr4.x = b2f(xrv.x); xr4.y = b2f(xrv.y); xr4.z = b2f(xrv.z); xr4.w = b2f(xrv.w);
  float4 o = gat_one(xl, xr4, d, rowstart[d], hist[d], mean_ea[d], lane,
                     csr_pack, w0, w1, at);
  o.x += bv.x; o.y += bv.y; o.z += bv.z; o.w += bv.w;
  if (relu) {
    o.x = fmaxf(o.x, 0.f); o.y = fmaxf(o.y, 0.f);
    o.z = fmaxf(o.z, 0.f); o.w = fmaxf(o.w, 0.f);
  }
  if (OUTBF) {
    ushort4 p4;
    p4.x = f2b(o.x); p4.y = f2b(o.y); p4.z = f2b(o.z); p4.w = f2b(o.w);
    *reinterpret_cast<ushort4*>((unsigned short*)out + (size_t)d * 128 + lane * 4) = p4;
  } else {
    *reinterpret_cast<float4*>((float*)out + (size_t)d * 128 + lane * 4) = o;
  }
}

// ------------------------- GCN per-node pull (batch-4) --------------------
__device__ __forceinline__ float4 gcn_one(
    const unsigned short* __restrict__ h, int d, int st, int deg, float dv, int lane,
    const int2* __restrict__ zcsr_pack, const float* __restrict__ dinv) {
  ushort4 hv = *reinterpret_cast<const ushort4*>(h + (size_t)d * 128 + lane * 4);
  float dv2 = dv * dv;
  float4 acc;
  acc.x = dv2 * b2f(hv.x); acc.y = dv2 * b2f(hv.y);
  acc.z = dv2 * b2f(hv.z); acc.w = dv2 * b2f(hv.w);
  for (int base = 0; base < deg; base += 32) {
    int rem = deg - base;
    int chunk = rem < 32 ? rem : 32;
    int k = st + base + lane;
    int sidx = 0;
    float wv = 0.f, dvs = 0.f;
    if (lane < chunk) {
      int2 pk = zcsr_pack[k];
      sidx = pk.x;
      wv = __int_as_float(pk.y);
      dvs = dinv[sidx];
    }
    auto edge = [&](ushort4 avv, int i) {
      float coef = __shfl(dvs, i, 32) * __shfl(wv, i, 32) * dv;
      acc.x += coef * b2f(avv.x); acc.y += coef * b2f(avv.y);
      acc.z += coef * b2f(avv.z); acc.w += coef * b2f(avv.w);
    };
    for (int i0 = 0; i0 < chunk; i0 += 4) {
      int cnt = chunk - i0; if (cnt > 4) cnt = 4;
      int s0 = __shfl(sidx, i0 + 0, 32);
      int s1 = __shfl(sidx, i0 + 1, 32);
      int s2 = __shfl(sidx, i0 + 2, 32);
      int s3 = __shfl(sidx, i0 + 3, 32);
      ushort4 a0, a1, a2, a3;
      a0 = *reinterpret_cast<const ushort4*>(h + (size_t)s0 * 128 + lane * 4);
      if (cnt > 1) a1 = *reinterpret_cast<const ushort4*>(h + (size_t)s1 * 128 + lane * 4);
      if (cnt > 2) a2 = *reinterpret_cast<const ushort4*>(h + (size_t)s2 * 128 + lane * 4);
      if (cnt > 3) a3 = *reinterpret_cast<const ushort4*>(h + (size_t)s3 * 128 + lane * 4);
      edge(a0, i0 + 0);
      if (cnt > 1) edge(a1, i0 + 1);
      if (cnt > 2) edge(a2, i0 + 2);
      if (cnt > 3) edge(a3, i0 + 3);
    }
  }
  return acc;
}

template <int OUTBF>
__global__ __launch_bounds__(256) void gcn_node(const unsigned short* __restrict__ h,
                                                const int* __restrict__ rowstart,
                                                const int* __restrict__ hist,
                                                const int2* __restrict__ zcsr_pack,
                                                const float* __restrict__ dinv,
                                                const float* __restrict__ bias, void* __restrict__ out,
                                                int NZ, int relu) {
  int t = threadIdx.x, grp = t >> 5, lane = t & 31;
  int d = blockIdx.x * 8 + grp;
  if (d >= NZ) return;
  float4 acc = gcn_one(h, d, rowstart[d], hist[d], dinv[d], lane, zcsr_pack, dinv);
  float4 bv = *reinterpret_cast<const float4*>(bias + lane * 4);
  float4 o;
  o.x = acc.x + bv.x; o.y = acc.y + bv.y; o.z = acc.z + bv.z; o.w = acc.w + bv.w;
  if (relu) {
    o.x = fmaxf(o.x, 0.f); o.y = fmaxf(o.y, 0.f);
    o.z = fmaxf(o.z, 0.f); o.w = fmaxf(o.w, 0.f);
  }
  if (OUTBF) {
    ushort4 p4;
    p4.x = f2b(o.x); p4.y = f2b(o.y); p4.z = f2b(o.z); p4.w = f2b(o.w);
    *reinterpret_cast<ushort4*>((unsigned short*)out + (size_t)d * 128 + lane * 4) = p4;
  } else {
    *reinterpret_cast<float4*>((float*)out + (size_t)d * 128 + lane * 4) = o;
  }
}

extern "C" void kernel_launch(void* const* d_in, const int* in_sizes, int n_in,
                              void* d_out, int out_size, void* d_ws, size_t ws_size,
                              hipStream_t stream) {
  const float* road_id_emb = (const float*)d_in[0];
  const float* len_W = (const float*)d_in[1];
  const float* len_b = (const float*)d_in[2];
  const float* type_emb = (const float*)d_in[3];
  const float* lon_W = (const float*)d_in[4];
  const float* lon_b = (const float*)d_in[5];
  const float* lat_W = (const float*)d_in[6];
  const float* lat_b = (const float*)d_in[7];
  const float* alen = (const float*)d_in[8];
  const int* atype = (const int*)d_in[9];
  const float* alon = (const float*)d_in[10];
  const float* alat = (const float*)d_in[11];
  const int* rei = (const int*)d_in[12];
  const float* ia = (const float*)d_in[13];
  const float* zone_emb = (const float*)d_in[28];
  const int* zei = (const int*)d_in[29];
  const float* zw = (const float*)d_in[30];
  const float* gcn1_W = (const float*)d_in[31];
  const float* gcn1_b = (const float*)d_in[32];
  const float* gcn2_W = (const float*)d_in[33];
  const float* gcn2_b = (const float*)d_in[34];

  const int N = in_sizes[8];          // 100000
  const int E = in_sizes[12] / 2;     // 400000
  const int NZ = in_sizes[28] / 128;  // 20000
  const int EZ = in_sizes[30];        // 160000

  const int* src = rei;
  const int* dst = rei + E;
  const int* zsrc = zei;
  const int* zdst = zei + EZ;

  // ---- workspace carve ----
  char* wp = (char*)d_ws;
  auto carve = [&](size_t bytes) {
    void* r = wp;
    wp += (bytes + 255) & ~(size_t)255;
    return r;
  };
  unsigned short* XRbf = (unsigned short*)carve((size_t)N * 128 * 2);  // xr1 / zone
  unsigned short* Abf = (unsigned short*)carve((size_t)N * 128 * 2);   // xr2
  unsigned short* Bbf = (unsigned short*)carve((size_t)N * 128 * 2);   // gat1 out
  unsigned short* Cbf = (unsigned short*)carve((size_t)N * 128 * 2);   // xl1 / xl2
  float2* mean_ea = (float2*)carve((size_t)N * 8);
  int* rowstart = (int*)carve((size_t)N * 4);
  int* zrowstart = (int*)carve((size_t)NZ * 4);
  int* hist = (int*)carve((size_t)N * 4);      // hist+zhist contiguous: one memset
  int* zhist = (int*)carve((size_t)NZ * 4);
  int* cursor = (int*)carve((size_t)N * 4);    // seeded by scan_add2
  int* zcursor = (int*)carve((size_t)NZ * 4);
  int4* csr_pack = (int4*)carve((size_t)E * 16);
  int2* zcsr_pack = (int2*)carve((size_t)EZ * 8);
  int* bsumR = (int*)carve(1024);
  int* bsumZ = (int*)carve(1024);
  float* dinv = (float*)carve((size_t)NZ * 4);
  unsigned short* WT = (unsigned short*)carve(6 * 16384 * 2);
  float* FL = (float*)carve(2 * 36 * 128 * 4);
  unsigned short* WT0 = WT;
  unsigned short* WT1 = WT + 16384;
  unsigned short* WT2 = WT + 2 * 16384;
  unsigned short* WT3 = WT + 3 * 16384;
  unsigned short* WT4 = WT + 4 * 16384;
  unsigned short* WT5 = WT + 5 * 16384;
  float* FLl = FL;
  float* FLr = FL + 36 * 128;

  float* road_out = (float*)d_out;
  float* zone_out = road_out + (size_t)N * 128;

  // ---- weight casts + feature folds ----
  wcast6<<<384, 256, 0, stream>>>(
      (const float*)d_in[14], (const float*)d_in[16], (const float*)d_in[21],
      (const float*)d_in[23], gcn1_W, gcn2_W, WT);
  feat_fold<<<72, 128, 0, stream>>>(
      (const float*)d_in[14], (const float*)d_in[15],
      (const float*)d_in[16], (const float*)d_in[17],
      len_W, len_b, type_emb, lon_W, lon_b, lat_W, lat_b, FL);

  // ---- CSR build (road + zone combined) ----
  const int nbR = (N + 1023) / 1024;
  const int nbZ = (NZ + 1023) / 1024;
  hipMemsetAsync(hist, 0, (size_t)((char*)(zhist + NZ) - (char*)hist), stream);
  hist2<<<(E + EZ + 255) / 256, 256, 0, stream>>>(dst, E, zdst, EZ, hist, zhist);
  scan_local2<<<nbR + nbZ, 256, 0, stream>>>(hist, rowstart, bsumR, N, nbR, zhist, zrowstart, bsumZ, NZ);
  scan_bsum2<<<2, 256, 0, stream>>>(bsumR, nbR, bsumZ, nbZ);
  scan_add2<<<(N + NZ + 255) / 256, 256, 0, stream>>>(
      rowstart, cursor, bsumR, N, zrowstart, zcursor, bsumZ, NZ);
  scatter2<<<(E + EZ + 255) / 256, 256, 0, stream>>>(
      src, dst, ia, cursor, csr_pack, E,
      zsrc, zdst, zw, zcursor, zcsr_pack, EZ);
  meanea_dinv_k<<<(N + NZ + 255) / 256, 256, 0, stream>>>(
      rowstart, hist, csr_pack, mean_ea, N, zrowstart, zhist, zcsr_pack, dinv, NZ);

  const int gemm_grid32 = (N + 31) / 32;
  const int node_grid = (N + 7) / 8;

  // road layer 1: id_emb K=64 GEMM + fold epilogue -> (xl1=Cbf, xr1=XRbf)
  feat_gemm1<<<gemm_grid32, 256, 0, stream>>>(
      road_id_emb, alen, atype, alon, alat,
      WT0, WT1, FLl, FLr, Cbf, XRbf, N);
  gat_node<1><<<node_grid, 256, 0, stream>>>(
      Cbf, XRbf, rowstart, hist, csr_pack, mean_ea,
      (const float*)d_in[18], (const float*)d_in[19], (const float*)d_in[20], Bbf, N, 1);
  // road layer 2: 32-row dual GEMM on Bbf -> (xl2=Cbf, xr2=Abf); gat2 -> road_out
  gemm_dual32<<<gemm_grid32, 256, 0, stream>>>(
      Bbf, WT2, WT3, (const float*)d_in[22], (const float*)d_in[24], Cbf, Abf, N);
  gat_node<0><<<node_grid, 256, 0, stream>>>(
      Cbf, Abf, rowstart, hist, csr_pack, mean_ea,
      (const float*)d_in[25], (const float*)d_in[26], (const float*)d_in[27], road_out, N, 0);

  // ---- zone chain (aliases XRbf region; road reads of XRbf done) ----
  unsigned short* HGbf = XRbf;
  unsigned short* ZAbf = XRbf + (size_t)NZ * 128;
  const int zgrid = (NZ + 63) / 64;
  const int znode_grid = (NZ + 7) / 8;
  gemm_mfma<0, 0><<<zgrid, 256, 0, stream>>>(zone_emb, WT4, nullptr, nullptr, nullptr, HGbf, nullptr, NZ);
  gcn_node<1><<<znode_grid, 256, 0, stream>>>(HGbf, zrowstart, zhist, zcsr_pack, dinv, gcn1_b, ZAbf, NZ, 1);
  gemm_mfma<0, 1><<<zgrid, 256, 0, stream>>>(ZAbf, WT5, nullptr, nullptr, nullptr, HGbf, nullptr, NZ);
  gcn_node<0><<<znode_grid, 256, 0, stream>>>(HGbf, zrowstart, zhist, zcsr_pack, dinv, gcn2_b, zone_out, NZ, 0);
}

// Round 17
// 264.413 us; speedup vs baseline: 1.0369x; 1.0369x over previous
//
#include <hip/hip_runtime.h>
#include <math.h>

// ---------------------------------------------------------------------------
// RoadNetworkEncoder: 2x GATv2 (road) + 2x GCN (zone), f32 in/out, H=128.
// Round 17: REVERT to round-15 config (best measured: 266us). Round-16's
// 32-row GEMM tiles regressed (274us; occupancy counter unmoved at 24% ->
// acc-reg theory falsified; added bank conflicts). This is round-15 verbatim:
// 64-row MT=4 dual GEMMs + packed CSR + fold-decomposed feat_gemm1 +
// batch-4 gather nodes + no-max softmax + LDS round-trip epilogues.
// ---------------------------------------------------------------------------

typedef __attribute__((ext_vector_type(8))) short bf16x8;
typedef __attribute__((ext_vector_type(4))) float f32x4;

static __device__ __forceinline__ unsigned short f2b(float f) {
  unsigned u = __float_as_uint(f);
  u = (u + 0x7FFFu + ((u >> 16) & 1u)) >> 16;  // RNE
  return (unsigned short)u;
}
static __device__ __forceinline__ float b2f(unsigned short u) {
  return __uint_as_float(((unsigned)u) << 16);
}

// ---- 6x W[128][128] f32 -> WT[n][k] bf16 (transpose + cast) ----
__global__ __launch_bounds__(256) void wcast6(
    const float* __restrict__ W0, const float* __restrict__ W1, const float* __restrict__ W2,
    const float* __restrict__ W3, const float* __restrict__ W4, const float* __restrict__ W5,
    unsigned short* __restrict__ WT) {
  int b = blockIdx.x >> 6;
  int idx = (blockIdx.x & 63) * 256 + threadIdx.x;
  const float* W = (b == 0) ? W0 : (b == 1) ? W1 : (b == 2) ? W2 : (b == 3) ? W3 : (b == 4) ? W4 : W5;
  int n = idx >> 7, k = idx & 127;
  WT[b * 16384 + idx] = f2b(W[k * 128 + n]);
}

// ---- fold the non-id feature segments: FL[mat][36][128] f32 --------------
__global__ __launch_bounds__(128) void feat_fold(
    const float* __restrict__ Wl, const float* __restrict__ blv,
    const float* __restrict__ Wr, const float* __restrict__ brv,
    const float* __restrict__ lenW, const float* __restrict__ lenb,
    const float* __restrict__ type_emb,
    const float* __restrict__ lonW, const float* __restrict__ lonb,
    const float* __restrict__ latW, const float* __restrict__ latb,
    float* __restrict__ FL) {
  int b = blockIdx.x;           // 0..71
  int mat = b / 36, r = b % 36;
  int n = threadIdx.x;          // 0..127
  const float* W = mat ? Wr : Wl;
  const float* bias = mat ? brv : blv;
  float s = 0.f;
  if (r < 32) {
#pragma unroll
    for (int j = 0; j < 16; ++j) s += type_emb[r * 16 + j] * W[(80 + j) * 128 + n];
  } else if (r == 32) {
#pragma unroll
    for (int j = 0; j < 16; ++j) s += lenW[j] * W[(64 + j) * 128 + n];
  } else if (r == 33) {
#pragma unroll
    for (int j = 0; j < 16; ++j) s += lonW[j] * W[(96 + j) * 128 + n];
  } else if (r == 34) {
#pragma unroll
    for (int j = 0; j < 16; ++j) s += latW[j] * W[(112 + j) * 128 + n];
  } else {
    s = bias[n];
#pragma unroll
    for (int j = 0; j < 16; ++j)
      s += lenb[j] * W[(64 + j) * 128 + n] + lonb[j] * W[(96 + j) * 128 + n] +
           latb[j] * W[(112 + j) * 128 + n];
  }
  FL[(mat * 36 + r) * 128 + n] = s;
}

// ------------------------- CSR build (road + zone combined) ---------------

__global__ __launch_bounds__(256) void hist2(const int* __restrict__ dstR, int E,
                                             const int* __restrict__ dstZ, int EZ,
                                             int* __restrict__ histR, int* __restrict__ histZ) {
  int e = blockIdx.x * 256 + threadIdx.x;
  if (e < E) atomicAdd(histR + dstR[e], 1);
  else if (e - E < EZ) atomicAdd(histZ + dstZ[e - E], 1);
}

__global__ __launch_bounds__(256) void scan_local2(
    const int* __restrict__ inR, int* __restrict__ outR, int* __restrict__ bsumR, int nR, int nbR,
    const int* __restrict__ inZ, int* __restrict__ outZ, int* __restrict__ bsumZ, int nZ) {
  __shared__ int lds[256];
  const int* in; int* out; int* bsum; int n; int bid;
  if ((int)blockIdx.x < nbR) { in = inR; out = outR; bsum = bsumR; n = nR; bid = blockIdx.x; }
  else { in = inZ; out = outZ; bsum = bsumZ; n = nZ; bid = blockIdx.x - nbR; }
  int t = threadIdx.x;
  int base = bid * 1024 + t * 4;
  int v0 = base + 0 < n ? in[base + 0] : 0;
  int v1 = base + 1 < n ? in[base + 1] : 0;
  int v2 = base + 2 < n ? in[base + 2] : 0;
  int v3 = base + 3 < n ? in[base + 3] : 0;
  int s = v0 + v1 + v2 + v3;
  lds[t] = s;
  __syncthreads();
  for (int off = 1; off < 256; off <<= 1) {
    int x = (t >= off) ? lds[t - off] : 0;
    __syncthreads();
    if (t >= off) lds[t] += x;
    __syncthreads();
  }
  int excl = lds[t] - s;
  if (t == 255) bsum[bid] = lds[255];
  if (base + 0 < n) out[base + 0] = excl;
  if (base + 1 < n) out[base + 1] = excl + v0;
  if (base + 2 < n) out[base + 2] = excl + v0 + v1;
  if (base + 3 < n) out[base + 3] = excl + v0 + v1 + v2;
}

__global__ __launch_bounds__(256) void scan_bsum2(int* __restrict__ bsumR, int nbR,
                                                  int* __restrict__ bsumZ, int nbZ) {
  __shared__ int lds[256];
  int* bsum = blockIdx.x ? bsumZ : bsumR;
  int nb = blockIdx.x ? nbZ : nbR;
  int t = threadIdx.x;
  int v = (t < nb) ? bsum[t] : 0;
  lds[t] = v;
  __syncthreads();
  for (int off = 1; off < 256; off <<= 1) {
    int x = (t >= off) ? lds[t - off] : 0;
    __syncthreads();
    if (t >= off) lds[t] += x;
    __syncthreads();
  }
  if (t < nb) bsum[t] = lds[t] - v;
}

// adds block offsets AND seeds cursor = rowstart
__global__ __launch_bounds__(256) void scan_add2(
    int* __restrict__ outR, int* __restrict__ curR, const int* __restrict__ bsumR, int nR,
    int* __restrict__ outZ, int* __restrict__ curZ, const int* __restrict__ bsumZ, int nZ) {
  int i = blockIdx.x * 256 + threadIdx.x;
  if (i < nR) {
    int v = outR[i] + bsumR[i >> 10];
    outR[i] = v;
    curR[i] = v;
  } else if (i - nR < nZ) {
    int j = i - nR;
    int v = outZ[j] + bsumZ[j >> 10];
    outZ[j] = v;
    curZ[j] = v;
  }
}

__global__ __launch_bounds__(256) void scatter2(
    const int* __restrict__ srcR, const int* __restrict__ dstR, const float* __restrict__ ia,
    int* __restrict__ cursor, int4* __restrict__ csr_pack, int E,
    const int* __restrict__ srcZ, const int* __restrict__ dstZ, const float* __restrict__ zw,
    int* __restrict__ zcursor, int2* __restrict__ zcsr_pack, int EZ) {
  int e = blockIdx.x * 256 + threadIdx.x;
  if (e < E) {
    int d = dstR[e];
    int idx = atomicAdd(cursor + d, 1);
    int4 pk;
    pk.x = srcR[e];
    pk.y = __float_as_int(ia[2 * e]);
    pk.z = __float_as_int(ia[2 * e + 1]);
    pk.w = 0;
    csr_pack[idx] = pk;
  } else if (e - E < EZ) {
    int ez = e - E;
    int d = dstZ[ez];
    int idx = atomicAdd(zcursor + d, 1);
    int2 pk;
    pk.x = srcZ[ez];
    pk.y = __float_as_int(zw[ez]);
    zcsr_pack[idx] = pk;
  }
}

__global__ __launch_bounds__(256) void meanea_dinv_k(
    const int* __restrict__ rowstart, const int* __restrict__ hist,
    const int4* __restrict__ csr_pack, float2* __restrict__ mea, int N,
    const int* __restrict__ zrowstart, const int* __restrict__ zhist,
    const int2* __restrict__ zcsr_pack, float* __restrict__ dinv, int NZ) {
  int i = blockIdx.x * 256 + threadIdx.x;
  if (i < N) {
    int st = rowstart[i], deg = hist[i];
    float a = 0.f, b = 0.f;
    for (int k = 0; k < deg; ++k) {
      int4 pk = csr_pack[st + k];
      a += __int_as_float(pk.y);
      b += __int_as_float(pk.z);
    }
    float c = deg > 0 ? 1.f / (float)deg : 0.f;
    mea[i] = make_float2(a * c, b * c);
  } else if (i - N < NZ) {
    int d = i - N;
    int st = zrowstart[d], deg = zhist[d];
    float s = 1.f;
    for (int k = 0; k < deg; ++k) s += __int_as_float(zcsr_pack[st + k].y);
    dinv[d] = rsqrtf(s);
  }
}

// ------------------------- shared GEMM core (swapped-operand MFMA) --------
template <int DUAL>
__device__ __forceinline__ void gemm_core(
    unsigned short (*Xs)[136],
    const unsigned short* __restrict__ WlT, const unsigned short* __restrict__ WrT,
    const float* __restrict__ bl, const float* __restrict__ br,
    unsigned short* __restrict__ Yl, unsigned short* __restrict__ Yr,
    int row0, int N) {
  constexpr int MT = DUAL ? 4 : 2;
  int t = threadIdx.x;
  int w = t >> 6, lane = t & 63;
  int mb = DUAL ? 0 : (w >> 1) * 2;
  int ncol0 = (w & 1) * 64;
  const bool isR = DUAL && (w >> 1);
  const unsigned short* WTw = isR ? WrT : WlT;
  const float* bias = isR ? br : bl;
  int l15 = lane & 15, l4 = lane >> 4;

  bf16x8 b0[4], b1[4];
#pragma unroll
  for (int nt = 0; nt < 4; ++nt) {
    const unsigned short* p = WTw + (size_t)(ncol0 + nt * 16 + l15) * 128 + l4 * 8;
    b0[nt] = *reinterpret_cast<const bf16x8*>(p);
  }
  f32x4 acc[MT][4];
#pragma unroll
  for (int mt = 0; mt < MT; ++mt)
#pragma unroll
    for (int nt = 0; nt < 4; ++nt)
      acc[mt][nt] = (f32x4){0.f, 0.f, 0.f, 0.f};

#pragma unroll
  for (int ks = 0; ks < 4; ++ks) {
    bf16x8* bc = (ks & 1) ? b1 : b0;
    bf16x8* bn = (ks & 1) ? b0 : b1;
    if (ks < 3) {
#pragma unroll
      for (int nt = 0; nt < 4; ++nt) {
        const unsigned short* p = WTw + (size_t)(ncol0 + nt * 16 + l15) * 128 + (ks + 1) * 32 + l4 * 8;
        bn[nt] = *reinterpret_cast<const bf16x8*>(p);
      }
    }
    bf16x8 a[MT];
#pragma unroll
    for (int mt = 0; mt < MT; ++mt)
      a[mt] = *reinterpret_cast<const bf16x8*>(&Xs[(mb + mt) * 16 + l15][ks * 32 + l4 * 8]);
#pragma unroll
    for (int mt = 0; mt < MT; ++mt)
#pragma unroll
      for (int nt = 0; nt < 4; ++nt)
        acc[mt][nt] = __builtin_amdgcn_mfma_f32_16x16x32_bf16(bc[nt], a[mt], acc[mt][nt], 0, 0, 0);
  }

  const int passes = DUAL ? 2 : 1;
#pragma unroll
  for (int pass = 0; pass < passes; ++pass) {
    __syncthreads();
    if (!DUAL || (w >> 1) == pass) {
#pragma unroll
      for (int nt = 0; nt < 4; ++nt) {
        int c0 = ncol0 + nt * 16 + l4 * 4;
        float4 bv = make_float4(0.f, 0.f, 0.f, 0.f);
        if (bias) bv = *reinterpret_cast<const float4*>(bias + c0);
#pragma unroll
        for (int mt = 0; mt < MT; ++mt) {
          int rl = (mb + mt) * 16 + l15;
          ushort4 pk;
          pk.x = f2b(acc[mt][nt][0] + bv.x);
          pk.y = f2b(acc[mt][nt][1] + bv.y);
          pk.z = f2b(acc[mt][nt][2] + bv.z);
          pk.w = f2b(acc[mt][nt][3] + bv.w);
          *reinterpret_cast<ushort4*>(&Xs[rl][c0]) = pk;
        }
      }
    }
    __syncthreads();
    unsigned short* Yt = DUAL ? (pass ? Yr : Yl) : Yl;
#pragma unroll
    for (int q = 0; q < 4; ++q) {
      int lin = q * 256 + t;
      int r = lin >> 4, cc = (lin & 15) * 8;
      int row = row0 + r;
      if (row < N)
        *reinterpret_cast<bf16x8*>(Yt + (size_t)row * 128 + cc) =
            *reinterpret_cast<const bf16x8*>(&Xs[r][cc]);
    }
  }
}

// ------------------------- standalone GEMM (XBF selects input type) -------
template <int DUAL, int XBF>
__global__ __launch_bounds__(256) void gemm_mfma(
    const void* __restrict__ Xv,
    const unsigned short* __restrict__ WlT, const unsigned short* __restrict__ WrT,
    const float* __restrict__ bl, const float* __restrict__ br,
    unsigned short* __restrict__ Yl, unsigned short* __restrict__ Yr, int N) {
  __shared__ __align__(16) unsigned short Xs[64][136];
  int t = threadIdx.x;
  int row0 = blockIdx.x * 64;
  if (XBF) {
    const unsigned short* Xb = (const unsigned short*)Xv;
#pragma unroll
    for (int q = 0; q < 8; ++q) {
      int lin = q * 256 + t;
      int r = lin >> 5, kf = (lin & 31) * 4;
      int row = min(row0 + r, N - 1);
      *reinterpret_cast<ushort4*>(&Xs[r][kf]) =
          *reinterpret_cast<const ushort4*>(Xb + (size_t)row * 128 + kf);
    }
  } else {
    const float* Xf = (const float*)Xv;
#pragma unroll
    for (int q = 0; q < 8; ++q) {
      int lin = q * 256 + t;
      int r = lin >> 5, kf = (lin & 31) * 4;
      int row = min(row0 + r, N - 1);
      float4 xv = *reinterpret_cast<const float4*>(Xf + (size_t)row * 128 + kf);
      ushort4 pk;
      pk.x = f2b(xv.x); pk.y = f2b(xv.y); pk.z = f2b(xv.z); pk.w = f2b(xv.w);
      *reinterpret_cast<ushort4*>(&Xs[r][kf]) = pk;
    }
  }
  __syncthreads();
  gemm_core<DUAL>(Xs, WlT, WrT, bl, br, Yl, Yr, row0, N);
}

// ------------------------- fused: id_emb K=64 GEMM + fold epilogue --------
__global__ __launch_bounds__(256) void feat_gemm1(
    const float* __restrict__ id_emb,
    const float* __restrict__ alen, const int* __restrict__ atype,
    const float* __restrict__ alon, const float* __restrict__ alat,
    const unsigned short* __restrict__ WlT, const unsigned short* __restrict__ WrT,
    const float* __restrict__ FLl, const float* __restrict__ FLr,
    unsigned short* __restrict__ Yl, unsigned short* __restrict__ Yr, int N) {
  __shared__ __align__(16) unsigned short Xs[64][136];
  int t = threadIdx.x;
  int row0 = blockIdx.x * 64;
  int w = t >> 6, lane = t & 63;
  int ncol0 = (w & 1) * 64;
  const bool isR = (w >> 1);
  const unsigned short* WTw = isR ? WrT : WlT;
  const float* FL = isR ? FLr : FLl;
  int l15 = lane & 15, l4 = lane >> 4;

  bf16x8 b0[4], b1[4];
#pragma unroll
  for (int nt = 0; nt < 4; ++nt) {
    const unsigned short* p = WTw + (size_t)(ncol0 + nt * 16 + l15) * 128 + l4 * 8;
    b0[nt] = *reinterpret_cast<const bf16x8*>(p);
    b1[nt] = *reinterpret_cast<const bf16x8*>(p + 32);
  }

#pragma unroll
  for (int q = 0; q < 4; ++q) {
    int lin = q * 256 + t;
    int r = lin >> 4, kf = (lin & 15) * 4;
    int row = min(row0 + r, N - 1);
    float4 xv = *reinterpret_cast<const float4*>(id_emb + (size_t)row * 64 + kf);
    ushort4 pk;
    pk.x = f2b(xv.x); pk.y = f2b(xv.y); pk.z = f2b(xv.z); pk.w = f2b(xv.w);
    *reinterpret_cast<ushort4*>(&Xs[r][kf]) = pk;
  }
  __syncthreads();

  f32x4 acc[4][4];
#pragma unroll
  for (int mt = 0; mt < 4; ++mt)
#pragma unroll
    for (int nt = 0; nt < 4; ++nt)
      acc[mt][nt] = (f32x4){0.f, 0.f, 0.f, 0.f};

#pragma unroll
  for (int ks = 0; ks < 2; ++ks) {
    bf16x8* bc = ks ? b1 : b0;
    bf16x8 a[4];
#pragma unroll
    for (int mt = 0; mt < 4; ++mt)
      a[mt] = *reinterpret_cast<const bf16x8*>(&Xs[mt * 16 + l15][ks * 32 + l4 * 8]);
#pragma unroll
    for (int mt = 0; mt < 4; ++mt)
#pragma unroll
      for (int nt = 0; nt < 4; ++nt)
        acc[mt][nt] = __builtin_amdgcn_mfma_f32_16x16x32_bf16(bc[nt], a[mt], acc[mt][nt], 0, 0, 0);
  }

  float lenv[4], lonv[4], latv[4];
  int tyv[4];
#pragma unroll
  for (int mt = 0; mt < 4; ++mt) {
    int row = min(row0 + mt * 16 + l15, N - 1);
    lenv[mt] = alen[row]; lonv[mt] = alon[row]; latv[mt] = alat[row];
    tyv[mt] = atype[row];
  }

#pragma unroll
  for (int pass = 0; pass < 2; ++pass) {
    __syncthreads();
    if ((int)isR == pass) {
#pragma unroll
      for (int nt = 0; nt < 4; ++nt) {
        int c0 = ncol0 + nt * 16 + l4 * 4;
        float4 vl = *reinterpret_cast<const float4*>(FL + 32 * 128 + c0);
        float4 vo = *reinterpret_cast<const float4*>(FL + 33 * 128 + c0);
        float4 va = *reinterpret_cast<const float4*>(FL + 34 * 128 + c0);
        float4 vc = *reinterpret_cast<const float4*>(FL + 35 * 128 + c0);
#pragma unroll
        for (int mt = 0; mt < 4; ++mt) {
          float4 tv = *reinterpret_cast<const float4*>(FL + tyv[mt] * 128 + c0);
          ushort4 pk;
          pk.x = f2b(acc[mt][nt][0] + lenv[mt] * vl.x + lonv[mt] * vo.x + latv[mt] * va.x + tv.x + vc.x);
          pk.y = f2b(acc[mt][nt][1] + lenv[mt] * vl.y + lonv[mt] * vo.y + latv[mt] * va.y + tv.y + vc.y);
          pk.z = f2b(acc[mt][nt][2] + lenv[mt] * vl.z + lonv[mt] * vo.z + latv[mt] * va.z + tv.z + vc.z);
          pk.w = f2b(acc[mt][nt][3] + lenv[mt] * vl.w + lonv[mt] * vo.w + latv[mt] * va.w + tv.w + vc.w);
          *reinterpret_cast<ushort4*>(&Xs[mt * 16 + l15][c0]) = pk;
        }
      }
    }
    __syncthreads();
    unsigned short* Yt = pass ? Yr : Yl;
#pragma unroll
    for (int q = 0; q < 4; ++q) {
      int lin = q * 256 + t;
      int r = lin >> 4, cc = (lin & 15) * 8;
      int row = row0 + r;
      if (row < N)
        *reinterpret_cast<bf16x8*>(Yt + (size_t)row * 128 + cc) =
            *reinterpret_cast<const bf16x8*>(&Xs[r][cc]);
    }
  }
}

// ------------------------- GAT per-node pull (no-max softmax, batch-4) ----
__device__ __forceinline__ float4 gat_one(
    const unsigned short* __restrict__ xl, float4 xr4,
    int d, int st, int deg, float2 me, int lane,
    const int4* __restrict__ csr_pack,
    float4 w0, float4 w1, float4 at) {
  float denom;
  float4 acc;
  {
    ushort4 av = *reinterpret_cast<const ushort4*>(xl + (size_t)d * 128 + lane * 4);
    float4 a;
    a.x = b2f(av.x); a.y = b2f(av.y); a.z = b2f(av.z); a.w = b2f(av.w);
    float4 v;
    v.x = a.x + xr4.x + me.x * w0.x + me.y * w1.x; v.x = v.x > 0.f ? v.x : 0.2f * v.x;
    v.y = a.y + xr4.y + me.x * w0.y + me.y * w1.y; v.y = v.y > 0.f ? v.y : 0.2f * v.y;
    v.z = a.z + xr4.z + me.x * w0.z + me.y * w1.z; v.z = v.z > 0.f ? v.z : 0.2f * v.z;
    v.w = a.w + xr4.w + me.x * w0.w + me.y * w1.w; v.w = v.w > 0.f ? v.w : 0.2f * v.w;
    float p = v.x * at.x + v.y * at.y + v.z * at.z + v.w * at.w;
#pragma unroll
    for (int off = 16; off; off >>= 1) p += __shfl_xor(p, off, 32);
    float wgt = __expf(p);
    denom = wgt;
    acc.x = wgt * a.x; acc.y = wgt * a.y; acc.z = wgt * a.z; acc.w = wgt * a.w;
  }
  for (int base = 0; base < deg; base += 32) {
    int rem = deg - base;
    int chunk = rem < 32 ? rem : 32;
    int k = st + base + lane;
    int sidx = 0;
    float2 eav = make_float2(0.f, 0.f);
    if (lane < chunk) {
      int4 pk = csr_pack[k];
      sidx = pk.x;
      eav = make_float2(__int_as_float(pk.y), __int_as_float(pk.z));
    }
    auto edge = [&](ushort4 avv, int i) {
      float ea0 = __shfl(eav.x, i, 32);
      float ea1 = __shfl(eav.y, i, 32);
      float4 a;
      a.x = b2f(avv.x); a.y = b2f(avv.y); a.z = b2f(avv.z); a.w = b2f(avv.w);
      float4 v;
      v.x = a.x + xr4.x + ea0 * w0.x + ea1 * w1.x; v.x = v.x > 0.f ? v.x : 0.2f * v.x;
      v.y = a.y + xr4.y + ea0 * w0.y + ea1 * w1.y; v.y = v.y > 0.f ? v.y : 0.2f * v.y;
      v.z = a.z + xr4.z + ea0 * w0.z + ea1 * w1.z; v.z = v.z > 0.f ? v.z : 0.2f * v.z;
      v.w = a.w + xr4.w + ea0 * w0.w + ea1 * w1.w; v.w = v.w > 0.f ? v.w : 0.2f * v.w;
      float p = v.x * at.x + v.y * at.y + v.z * at.z + v.w * at.w;
#pragma unroll
      for (int off = 16; off; off >>= 1) p += __shfl_xor(p, off, 32);
      float wgt = __expf(p);
      denom += wgt;
      acc.x += wgt * a.x; acc.y += wgt * a.y; acc.z += wgt * a.z; acc.w += wgt * a.w;
    };
    for (int i0 = 0; i0 < chunk; i0 += 4) {
      int cnt = chunk - i0; if (cnt > 4) cnt = 4;
      int s0 = __shfl(sidx, i0 + 0, 32);
      int s1 = __shfl(sidx, i0 + 1, 32);
      int s2 = __shfl(sidx, i0 + 2, 32);
      int s3 = __shfl(sidx, i0 + 3, 32);
      ushort4 a0, a1, a2, a3;
      a0 = *reinterpret_cast<const ushort4*>(xl + (size_t)s0 * 128 + lane * 4);
      if (cnt > 1) a1 = *reinterpret_cast<const ushort4*>(xl + (size_t)s1 * 128 + lane * 4);
      if (cnt > 2) a2 = *reinterpret_cast<const ushort4*>(xl + (size_t)s2 * 128 + lane * 4);
      if (cnt > 3) a3 = *reinterpret_cast<const ushort4*>(xl + (size_t)s3 * 128 + lane * 4);
      edge(a0, i0 + 0);
      if (cnt > 1) edge(a1, i0 + 1);
      if (cnt > 2) edge(a2, i0 + 2);
      if (cnt > 3) edge(a3, i0 + 3);
    }
  }
  float inv = 1.f / denom;
  float4 o;
  o.x = acc.x * inv; o.y = acc.y * inv; o.z = acc.z * inv; o.w = acc.w * inv;
  return o;
}

template <int OUTBF>
__global__ __launch_bounds__(256) void gat_node(
    const unsigned short* __restrict__ xl, const unsigned short* __restrict__ xr,
    const int* __restrict__ rowstart, const int* __restrict__ hist,
    const int4* __restrict__ csr_pack,
    const float2* __restrict__ mean_ea,
    const float* __restrict__ We, const float* __restrict__ att, const float* __restrict__ bias,
    void* __restrict__ out, int N, int relu) {
  __shared__ float sW0[128], sW1[128], sAtt[128], sBias[128];
  int t = threadIdx.x;
  if (t < 128) { sW0[t] = We[t]; sW1[t] = We[128 + t]; }
  else { int j = t - 128; sAtt[j] = att[j]; sBias[j] = bias[j]; }
  __syncthreads();
  int grp = t >> 5, lane = t & 31;
  int d = blockIdx.x * 8 + grp;
  if (d >= N) return;
  float4 w0 = *reinterpret_cast<const float4*>(sW0 + lane * 4);
  float4 w1 = *reinterpret_cast<const float4*>(sW1 + lane * 4);
  float4 at = *reinterpret_cast<const float4*>(sAtt + lane * 4);
  float4 bv = *reinterpret_cast<const float4*>(sBias + lane * 4);
  ushort4 xrv = *reinterpret_cast<const ushort4*>(xr + (size_t)d * 128 + lane * 4);
  float4 xr4;
  xr4.x = b2f(xrv.x); xr4.y = b2f(xrv.y); xr4.z = b2f(xrv.z); xr4.w = b2f(xrv.w);
  float4 o = gat_one(xl, xr4, d, rowstart[d], hist[d], mean_ea[d], lane,
                     csr_pack, w0, w1, at);
  o.x += bv.x; o.y += bv.y; o.z += bv.z; o.w += bv.w;
  if (relu) {
    o.x = fmaxf(o.x, 0.f); o.y = fmaxf(o.y, 0.f);
    o.z = fmaxf(o.z, 0.f); o.w = fmaxf(o.w, 0.f);
  }
  if (OUTBF) {
    ushort4 p4;
    p4.x = f2b(o.x); p4.y = f2b(o.y); p4.z = f2b(o.z); p4.w = f2b(o.w);
    *reinterpret_cast<ushort4*>((unsigned short*)out + (size_t)d * 128 + lane * 4) = p4;
  } else {
    *reinterpret_cast<float4*>((float*)out + (size_t)d * 128 + lane * 4) = o;
  }
}

// ------------------------- GCN per-node pull (batch-4) --------------------
__device__ __forceinline__ float4 gcn_one(
    const unsigned short* __restrict__ h, int d, int st, int deg, float dv, int lane,
    const int2* __restrict__ zcsr_pack, const float* __restrict__ dinv) {
  ushort4 hv = *reinterpret_cast<const ushort4*>(h + (size_t)d * 128 + lane * 4);
  float dv2 = dv * dv;
  float4 acc;
  acc.x = dv2 * b2f(hv.x); acc.y = dv2 * b2f(hv.y);
  acc.z = dv2 * b2f(hv.z); acc.w = dv2 * b2f(hv.w);
  for (int base = 0; base < deg; base += 32) {
    int rem = deg - base;
    int chunk = rem < 32 ? rem : 32;
    int k = st + base + lane;
    int sidx = 0;
    float wv = 0.f, dvs = 0.f;
    if (lane < chunk) {
      int2 pk = zcsr_pack[k];
      sidx = pk.x;
      wv = __int_as_float(pk.y);
      dvs = dinv[sidx];
    }
    auto edge = [&](ushort4 avv, int i) {
      float coef = __shfl(dvs, i, 32) * __shfl(wv, i, 32) * dv;
      acc.x += coef * b2f(avv.x); acc.y += coef * b2f(avv.y);
      acc.z += coef * b2f(avv.z); acc.w += coef * b2f(avv.w);
    };
    for (int i0 = 0; i0 < chunk; i0 += 4) {
      int cnt = chunk - i0; if (cnt > 4) cnt = 4;
      int s0 = __shfl(sidx, i0 + 0, 32);
      int s1 = __shfl(sidx, i0 + 1, 32);
      int s2 = __shfl(sidx, i0 + 2, 32);
      int s3 = __shfl(sidx, i0 + 3, 32);
      ushort4 a0, a1, a2, a3;
      a0 = *reinterpret_cast<const ushort4*>(h + (size_t)s0 * 128 + lane * 4);
      if (cnt > 1) a1 = *reinterpret_cast<const ushort4*>(h + (size_t)s1 * 128 + lane * 4);
      if (cnt > 2) a2 = *reinterpret_cast<const ushort4*>(h + (size_t)s2 * 128 + lane * 4);
      if (cnt > 3) a3 = *reinterpret_cast<const ushort4*>(h + (size_t)s3 * 128 + lane * 4);
      edge(a0, i0 + 0);
      if (cnt > 1) edge(a1, i0 + 1);
      if (cnt > 2) edge(a2, i0 + 2);
      if (cnt > 3) edge(a3, i0 + 3);
    }
  }
  return acc;
}

template <int OUTBF>
__global__ __launch_bounds__(256) void gcn_node(const unsigned short* __restrict__ h,
                                                const int* __restrict__ rowstart,
                                                const int* __restrict__ hist,
                                                const int2* __restrict__ zcsr_pack,
                                                const float* __restrict__ dinv,
                                                const float* __restrict__ bias, void* __restrict__ out,
                                                int NZ, int relu) {
  int t = threadIdx.x, grp = t >> 5, lane = t & 31;
  int d = blockIdx.x * 8 + grp;
  if (d >= NZ) return;
  float4 acc = gcn_one(h, d, rowstart[d], hist[d], dinv[d], lane, zcsr_pack, dinv);
  float4 bv = *reinterpret_cast<const float4*>(bias + lane * 4);
  float4 o;
  o.x = acc.x + bv.x; o.y = acc.y + bv.y; o.z = acc.z + bv.z; o.w = acc.w + bv.w;
  if (relu) {
    o.x = fmaxf(o.x, 0.f); o.y = fmaxf(o.y, 0.f);
    o.z = fmaxf(o.z, 0.f); o.w = fmaxf(o.w, 0.f);
  }
  if (OUTBF) {
    ushort4 p4;
    p4.x = f2b(o.x); p4.y = f2b(o.y); p4.z = f2b(o.z); p4.w = f2b(o.w);
    *reinterpret_cast<ushort4*>((unsigned short*)out + (size_t)d * 128 + lane * 4) = p4;
  } else {
    *reinterpret_cast<float4*>((float*)out + (size_t)d * 128 + lane * 4) = o;
  }
}

extern "C" void kernel_launch(void* const* d_in, const int* in_sizes, int n_in,
                              void* d_out, int out_size, void* d_ws, size_t ws_size,
                              hipStream_t stream) {
  const float* road_id_emb = (const float*)d_in[0];
  const float* len_W = (const float*)d_in[1];
  const float* len_b = (const float*)d_in[2];
  const float* type_emb = (const float*)d_in[3];
  const float* lon_W = (const float*)d_in[4];
  const float* lon_b = (const float*)d_in[5];
  const float* lat_W = (const float*)d_in[6];
  const float* lat_b = (const float*)d_in[7];
  const float* alen = (const float*)d_in[8];
  const int* atype = (const int*)d_in[9];
  const float* alon = (const float*)d_in[10];
  const float* alat = (const float*)d_in[11];
  const int* rei = (const int*)d_in[12];
  const float* ia = (const float*)d_in[13];
  const float* zone_emb = (const float*)d_in[28];
  const int* zei = (const int*)d_in[29];
  const float* zw = (const float*)d_in[30];
  const float* gcn1_W = (const float*)d_in[31];
  const float* gcn1_b = (const float*)d_in[32];
  const float* gcn2_W = (const float*)d_in[33];
  const float* gcn2_b = (const float*)d_in[34];

  const int N = in_sizes[8];          // 100000
  const int E = in_sizes[12] / 2;     // 400000
  const int NZ = in_sizes[28] / 128;  // 20000
  const int EZ = in_sizes[30];        // 160000

  const int* src = rei;
  const int* dst = rei + E;
  const int* zsrc = zei;
  const int* zdst = zei + EZ;

  // ---- workspace carve ----
  char* wp = (char*)d_ws;
  auto carve = [&](size_t bytes) {
    void* r = wp;
    wp += (bytes + 255) & ~(size_t)255;
    return r;
  };
  unsigned short* XRbf = (unsigned short*)carve((size_t)N * 128 * 2);  // xr1 / zone
  unsigned short* Abf = (unsigned short*)carve((size_t)N * 128 * 2);   // xr2
  unsigned short* Bbf = (unsigned short*)carve((size_t)N * 128 * 2);   // gat1 out
  unsigned short* Cbf = (unsigned short*)carve((size_t)N * 128 * 2);   // xl1 / xl2
  float2* mean_ea = (float2*)carve((size_t)N * 8);
  int* rowstart = (int*)carve((size_t)N * 4);
  int* zrowstart = (int*)carve((size_t)NZ * 4);
  int* hist = (int*)carve((size_t)N * 4);      // hist+zhist contiguous: one memset
  int* zhist = (int*)carve((size_t)NZ * 4);
  int* cursor = (int*)carve((size_t)N * 4);    // seeded by scan_add2
  int* zcursor = (int*)carve((size_t)NZ * 4);
  int4* csr_pack = (int4*)carve((size_t)E * 16);
  int2* zcsr_pack = (int2*)carve((size_t)EZ * 8);
  int* bsumR = (int*)carve(1024);
  int* bsumZ = (int*)carve(1024);
  float* dinv = (float*)carve((size_t)NZ * 4);
  unsigned short* WT = (unsigned short*)carve(6 * 16384 * 2);
  float* FL = (float*)carve(2 * 36 * 128 * 4);
  unsigned short* WT0 = WT;
  unsigned short* WT1 = WT + 16384;
  unsigned short* WT2 = WT + 2 * 16384;
  unsigned short* WT3 = WT + 3 * 16384;
  unsigned short* WT4 = WT + 4 * 16384;
  unsigned short* WT5 = WT + 5 * 16384;
  float* FLl = FL;
  float* FLr = FL + 36 * 128;

  float* road_out = (float*)d_out;
  float* zone_out = road_out + (size_t)N * 128;

  // ---- weight casts + feature folds ----
  wcast6<<<384, 256, 0, stream>>>(
      (const float*)d_in[14], (const float*)d_in[16], (const float*)d_in[21],
      (const float*)d_in[23], gcn1_W, gcn2_W, WT);
  feat_fold<<<72, 128, 0, stream>>>(
      (const float*)d_in[14], (const float*)d_in[15],
      (const float*)d_in[16], (const float*)d_in[17],
      len_W, len_b, type_emb, lon_W, lon_b, lat_W, lat_b, FL);

  // ---- CSR build (road + zone combined) ----
  const int nbR = (N + 1023) / 1024;
  const int nbZ = (NZ + 1023) / 1024;
  hipMemsetAsync(hist, 0, (size_t)((char*)(zhist + NZ) - (char*)hist), stream);
  hist2<<<(E + EZ + 255) / 256, 256, 0, stream>>>(dst, E, zdst, EZ, hist, zhist);
  scan_local2<<<nbR + nbZ, 256, 0, stream>>>(hist, rowstart, bsumR, N, nbR, zhist, zrowstart, bsumZ, NZ);
  scan_bsum2<<<2, 256, 0, stream>>>(bsumR, nbR, bsumZ, nbZ);
  scan_add2<<<(N + NZ + 255) / 256, 256, 0, stream>>>(
      rowstart, cursor, bsumR, N, zrowstart, zcursor, bsumZ, NZ);
  scatter2<<<(E + EZ + 255) / 256, 256, 0, stream>>>(
      src, dst, ia, cursor, csr_pack, E,
      zsrc, zdst, zw, zcursor, zcsr_pack, EZ);
  meanea_dinv_k<<<(N + NZ + 255) / 256, 256, 0, stream>>>(
      rowstart, hist, csr_pack, mean_ea, N, zrowstart, zhist, zcsr_pack, dinv, NZ);

  const int gemm_grid = (N + 63) / 64;
  const int node_grid = (N + 7) / 8;

  // road layer 1: id_emb K=64 GEMM + fold epilogue -> (xl1=Cbf, xr1=XRbf)
  feat_gemm1<<<gemm_grid, 256, 0, stream>>>(
      road_id_emb, alen, atype, alon, alat,
      WT0, WT1, FLl, FLr, Cbf, XRbf, N);
  gat_node<1><<<node_grid, 256, 0, stream>>>(
      Cbf, XRbf, rowstart, hist, csr_pack, mean_ea,
      (const float*)d_in[18], (const float*)d_in[19], (const float*)d_in[20], Bbf, N, 1);
  // road layer 2: GEMM on Bbf -> (xl2=Cbf, xr2=Abf); gat2 -> road_out
  gemm_mfma<1, 1><<<gemm_grid, 256, 0, stream>>>(
      Bbf, WT2, WT3, (const float*)d_in[22], (const float*)d_in[24], Cbf, Abf, N);
  gat_node<0><<<node_grid, 256, 0, stream>>>(
      Cbf, Abf, rowstart, hist, csr_pack, mean_ea,
      (const float*)d_in[25], (const float*)d_in[26], (const float*)d_in[27], road_out, N, 0);

  // ---- zone chain (aliases XRbf region; road reads of XRbf done) ----
  unsigned short* HGbf = XRbf;
  unsigned short* ZAbf = XRbf + (size_t)NZ * 128;
  const int zgrid = (NZ + 63) / 64;
  const int znode_grid = (NZ + 7) / 8;
  gemm_mfma<0, 0><<<zgrid, 256, 0, stream>>>(zone_emb, WT4, nullptr, nullptr, nullptr, HGbf, nullptr, NZ);
  gcn_node<1><<<znode_grid, 256, 0, stream>>>(HGbf, zrowstart, zhist, zcsr_pack, dinv, gcn1_b, ZAbf, NZ, 1);
  gemm_mfma<0, 1><<<zgrid, 256, 0, stream>>>(ZAbf, WT5, nullptr, nullptr, nullptr, HGbf, nullptr, NZ);
  gcn_node<0><<<znode_grid, 256, 0, stream>>>(HGbf, zrowstart, zhist, zcsr_pack, dinv, gcn2_b, zone_out, NZ, 0);
}